// Round 13
// baseline (475.813 us; speedup 1.0000x reference)
//
#include <hip/hip_runtime.h>
#include <hip/hip_bf16.h>
#include <math.h>

#define IN_F 128
#define HID 64
#define HEADS 4
#define HD0 (HEADS * HID)   // 256
#define OUT_F 64
#define NOISE_SCALE 2.5372725354060904f

typedef __bf16 bf16x8 __attribute__((ext_vector_type(8)));
typedef float f32x4 __attribute__((ext_vector_type(4)));
typedef float f4 __attribute__((ext_vector_type(4)));
typedef unsigned int u4 __attribute__((ext_vector_type(4)));

__device__ __forceinline__ float bf2f(unsigned short u) {
    return __uint_as_float(((unsigned)u) << 16);
}
__device__ __forceinline__ unsigned short f2bf(float f) {
    unsigned u = __float_as_uint(f);
    u = u + 0x7fffu + ((u >> 16) & 1u);  // round-nearest-even
    return (unsigned short)(u >> 16);
}

// accumulate 8 bf16 features (packed in uint4) scaled by weight
__device__ __forceinline__ void acc8(float* acc, const uint4& u, float wt) {
    acc[0] += wt * __uint_as_float(u.x << 16);
    acc[1] += wt * __uint_as_float(u.x & 0xffff0000u);
    acc[2] += wt * __uint_as_float(u.y << 16);
    acc[3] += wt * __uint_as_float(u.y & 0xffff0000u);
    acc[4] += wt * __uint_as_float(u.z << 16);
    acc[5] += wt * __uint_as_float(u.z & 0xffff0000u);
    acc[6] += wt * __uint_as_float(u.w << 16);
    acc[7] += wt * __uint_as_float(u.w & 0xffff0000u);
}

// pack 8 fp32 -> 8 bf16 (uint4)
__device__ __forceinline__ uint4 pack8(const float4& a, const float4& b) {
    uint4 r;
    r.x = (unsigned)f2bf(a.x) | ((unsigned)f2bf(a.y) << 16);
    r.y = (unsigned)f2bf(a.z) | ((unsigned)f2bf(a.w) << 16);
    r.z = (unsigned)f2bf(b.x) | ((unsigned)f2bf(b.y) << 16);
    r.w = (unsigned)f2bf(b.z) | ((unsigned)f2bf(b.w) << 16);
    return r;
}

// ---------- prep: W0/W1 transpose-cast + zero deg + zero scan flags ----------
__global__ __launch_bounds__(256) void prep_kernel(
    int* __restrict__ deg, int N,
    unsigned long long* __restrict__ combo, int ntiles,
    const float* __restrict__ W0, unsigned short* __restrict__ W0t,
    const float* __restrict__ W1, unsigned short* __restrict__ W1t) {
    const int b = blockIdx.x;
    int i = b * 256 + threadIdx.x;
    if (i < N) deg[i] = 0;
    if (i < ntiles) combo[i] = 0ULL;
    if (b < (IN_F * HD0) / 256) {            // 128 blocks
        int n = i / IN_F, k = i % IN_F;
        W0t[i] = f2bf(W0[(size_t)k * HD0 + n]);
    } else if (b < (IN_F * HD0) / 256 + (HD0 * OUT_F) / 256) {  // next 64
        int j = i - IN_F * HD0;
        int n = j / HD0, k = j % HD0;
        W1t[j] = f2bf(W1[(size_t)k * OUT_F + n]);
    }
}

// ---------- Layer-0 GEMM: NT=4 (full 256 cols/block), x read ONCE ----------
// A (fp32) staged whole into LDS with cast (2 barriers total);
// B (W0t, 64KB) read directly from global (L1/L2-resident, same for all blocks);
// scattered 2B C-stores (R2-proven epilogue) + fused el/er.
__global__ __launch_bounds__(256) void gemm0_kernel(
    const float* __restrict__ x, const unsigned short* __restrict__ Bt,
    unsigned short* __restrict__ C, const float* __restrict__ al,
    const float* __restrict__ ar, float* __restrict__ el,
    float* __restrict__ er, int M) {
    constexpr int K = IN_F;          // 128
    constexpr int ASTR = K + 8;      // 136 shorts
    __shared__ __align__(16) unsigned short As[128 * ASTR];   // 34.8 KB
    const int tid = threadIdx.x;
    const int lane = tid & 63, w = tid >> 6;
    const int row0 = blockIdx.x * 128;
    const int q = lane >> 4, c = lane & 15;
    const int r_st = tid >> 1, hh = tid & 1;
    // ---- stage whole A tile (fp32 -> bf16), one barrier ----
    {
        const int gr = row0 + r_st;
        const float* xp = x + (size_t)gr * K + hh * 16;
        unsigned short* ap = As + r_st * ASTR + hh * 16;
#pragma unroll
        for (int k0 = 0; k0 < K; k0 += 32) {
            uint4 av0 = make_uint4(0, 0, 0, 0), av1 = make_uint4(0, 0, 0, 0);
            if (gr < M) {
                const float4 fa = *(const float4*)(xp + k0);
                const float4 fb = *(const float4*)(xp + k0 + 4);
                const float4 fc = *(const float4*)(xp + k0 + 8);
                const float4 fd = *(const float4*)(xp + k0 + 12);
                av0 = pack8(fa, fb);
                av1 = pack8(fc, fd);
            }
            *(uint4*)(ap + k0) = av0;
            *(uint4*)(ap + k0 + 8) = av1;
        }
    }
    __syncthreads();
    // ---- MFMA main loop: B fragments straight from global ----
    f32x4 acc[2][16] = {};
#pragma unroll
    for (int k0 = 0; k0 < K; k0 += 32) {
        const bf16x8 af0 = *(const bf16x8*)(As + (w * 32 + c) * ASTR + k0 + q * 8);
        const bf16x8 af1 = *(const bf16x8*)(As + (w * 32 + 16 + c) * ASTR + k0 + q * 8);
#pragma unroll
        for (int nt = 0; nt < 16; ++nt) {
            const bf16x8 bfr =
                *(const bf16x8*)(Bt + (size_t)(nt * 16 + c) * K + k0 + q * 8);
            acc[0][nt] = __builtin_amdgcn_mfma_f32_16x16x32_bf16(
                af0, bfr, acc[0][nt], 0, 0, 0);
            acc[1][nt] = __builtin_amdgcn_mfma_f32_16x16x32_bf16(
                af1, bfr, acc[1][nt], 0, 0, 0);
        }
    }
    // ---- epilogue: scattered C stores + el/er (R2-proven pattern) ----
    float alv[16], arv[16];
#pragma unroll
    for (int nt = 0; nt < 16; ++nt) {
        alv[nt] = al[nt * 16 + c];
        arv[nt] = ar[nt * 16 + c];
    }
#pragma unroll
    for (int mt = 0; mt < 2; ++mt) {
#pragma unroll
        for (int r = 0; r < 4; ++r) {
            const int grow = row0 + w * 32 + mt * 16 + q * 4 + r;
            const bool ok = grow < M;
#pragma unroll
            for (int g = 0; g < 4; ++g) {
                float elp = 0.f, erp = 0.f;
#pragma unroll
                for (int t = 0; t < 4; ++t) {
                    int nt = g * 4 + t;
                    float v = acc[mt][nt][r];
                    elp += v * alv[nt];
                    erp += v * arv[nt];
                    if (ok) C[(size_t)grow * HD0 + nt * 16 + c] = f2bf(v);
                }
#pragma unroll
                for (int o = 8; o > 0; o >>= 1) {
                    elp += __shfl_down(elp, o, 16);
                    erp += __shfl_down(erp, o, 16);
                }
                if (c == 0 && ok) {
                    el[(size_t)grow * HEADS + g] = elp;
                    er[(size_t)grow * HEADS + g] = erp;
                }
            }
        }
    }
}

// ---------- generic MFMA GEMM + fused el/er (layer 1, NT=1) ----------
template <int K, int H, int NT, bool CVT>
__global__ __launch_bounds__(256) void gemm_fused_kernel(
    const void* __restrict__ Asrc, const unsigned short* __restrict__ Bt,
    unsigned short* __restrict__ C, const float* __restrict__ al,
    const float* __restrict__ ar, float* __restrict__ el,
    float* __restrict__ er, int M, int NC) {
    constexpr int BSTR = K + 8;
    constexpr int ASTR = 40;
    constexpr int NROWS = 64 * NT;
    constexpr int CSTR = NROWS + 8;
    __shared__ __align__(16) unsigned short Bs[NROWS * BSTR];
    __shared__ __align__(16) unsigned short As[128 * ASTR];
    const unsigned short* Ab = (const unsigned short*)Asrc;
    const float* Af = (const float*)Asrc;
    const int tid = threadIdx.x;
    const int lane = tid & 63, w = tid >> 6;
    const int row0 = blockIdx.y * 128;
    const int n0 = blockIdx.x * NROWS;
    for (int i = tid; i < NROWS * (K / 8); i += 256) {
        int n = i / (K / 8), kc = i % (K / 8);
        *(uint4*)(Bs + n * BSTR + kc * 8) =
            *(const uint4*)(Bt + (size_t)(n0 + n) * K + kc * 8);
    }
    f32x4 acc[2][4 * NT] = {};
    const int q = lane >> 4, c = lane & 15;
    const int r_st = tid >> 1, hh = tid & 1;
    for (int k0 = 0; k0 < K; k0 += 32) {
        int gr = row0 + r_st;
        uint4 av0 = make_uint4(0, 0, 0, 0), av1 = make_uint4(0, 0, 0, 0);
        if (gr < M) {
            if (CVT) {
                const float* xp = Af + (size_t)gr * K + k0 + hh * 16;
                const float4 fa = *(const float4*)xp;
                const float4 fb = *(const float4*)(xp + 4);
                const float4 fc = *(const float4*)(xp + 8);
                const float4 fd = *(const float4*)(xp + 12);
                av0 = pack8(fa, fb);
                av1 = pack8(fc, fd);
            } else {
                const unsigned short* ap = Ab + (size_t)gr * K + k0 + hh * 16;
                av0 = *(const uint4*)(ap);
                av1 = *(const uint4*)(ap + 8);
            }
        }
        __syncthreads();
        *(uint4*)(As + r_st * ASTR + hh * 16) = av0;
        *(uint4*)(As + r_st * ASTR + hh * 16 + 8) = av1;
        __syncthreads();
        bf16x8 af[2], bfr[4 * NT];
        af[0] = *(const bf16x8*)(As + (w * 32 + c) * ASTR + q * 8);
        af[1] = *(const bf16x8*)(As + (w * 32 + 16 + c) * ASTR + q * 8);
#pragma unroll
        for (int nt = 0; nt < 4 * NT; ++nt)
            bfr[nt] = *(const bf16x8*)(Bs + (nt * 16 + c) * BSTR + k0 + q * 8);
#pragma unroll
        for (int mt = 0; mt < 2; ++mt)
#pragma unroll
            for (int nt = 0; nt < 4 * NT; ++nt)
                acc[mt][nt] = __builtin_amdgcn_mfma_f32_16x16x32_bf16(
                    af[mt], bfr[nt], acc[mt][nt], 0, 0, 0);
    }
    float alv[4 * NT], arv[4 * NT];
#pragma unroll
    for (int nt = 0; nt < 4 * NT; ++nt) {
        alv[nt] = al[n0 + nt * 16 + c];
        arv[nt] = ar[n0 + nt * 16 + c];
    }
    __syncthreads();
    unsigned short* Cs = Bs;
    const int headbase = n0 >> 6;
#pragma unroll
    for (int mt = 0; mt < 2; ++mt) {
#pragma unroll
        for (int r = 0; r < 4; ++r) {
            const int row = w * 32 + mt * 16 + q * 4 + r;
            const int grow = row0 + row;
            const bool ok = grow < M;
#pragma unroll
            for (int g = 0; g < NT; ++g) {
                float elp = 0.f, erp = 0.f;
#pragma unroll
                for (int t = 0; t < 4; ++t) {
                    int nt = g * 4 + t;
                    float v = acc[mt][nt][r];
                    elp += v * alv[nt];
                    erp += v * arv[nt];
                    Cs[row * CSTR + nt * 16 + c] = f2bf(v);
                }
#pragma unroll
                for (int o = 8; o > 0; o >>= 1) {
                    elp += __shfl_down(elp, o, 16);
                    erp += __shfl_down(erp, o, 16);
                }
                if (c == 0 && ok) {
                    el[(size_t)grow * H + headbase + g] = elp;
                    er[(size_t)grow * H + headbase + g] = erp;
                }
            }
        }
    }
    __syncthreads();
    constexpr int CPR = NROWS / 8;
    for (int i = tid; i < 128 * CPR; i += 256) {
        int row = i / CPR, ch = i % CPR;
        int grow = row0 + row;
        if (grow < M)
            *(uint4*)(C + (size_t)grow * NC + n0 + ch * 8) =
                *(const uint4*)(Cs + row * CSTR + ch * 8);
    }
}

// ================= CSR build =================
__global__ __launch_bounds__(256) void degree_kernel(
    const int* __restrict__ dst, int* __restrict__ deg, int E) {
    int e = blockIdx.x * 256 + threadIdx.x;
    if (e < E) atomicAdd(&deg[dst[e]], 1);
}

// single-pass scan with decoupled lookback
__global__ __launch_bounds__(256) void scan_fused_kernel(
    const int* __restrict__ deg, int* __restrict__ off, int* __restrict__ cur,
    unsigned long long* __restrict__ combo, int N, int E) {
    const int t = blockIdx.x;
    __shared__ int s[256];
    __shared__ int sbase;
    const int tid = threadIdx.x;
    const int i = t * 256 + tid;
    const int v = (i < N) ? deg[i] : 0;
    s[tid] = v;
    __syncthreads();
    for (int d = 1; d < 256; d <<= 1) {
        int tt = (tid >= d) ? s[tid - d] : 0;
        __syncthreads();
        s[tid] += tt;
        __syncthreads();
    }
    const int tilesum = s[255];
    if (tid == 0) {
        if (t == 0) {
            atomicExch(&combo[0], (2ULL << 32) | (unsigned)tilesum);
            sbase = 0;
        } else {
            atomicExch(&combo[t], (1ULL << 32) | (unsigned)tilesum);
            int run = 0;
            int j = t - 1;
            while (true) {
                unsigned long long c;
                do {
                    c = atomicAdd(&combo[j], 0ULL);
                } while ((c >> 32) == 0ULL);
                run += (int)(c & 0xffffffffULL);
                if ((c >> 32) == 2ULL) break;
                --j;
            }
            sbase = run;
            atomicExch(&combo[t], (2ULL << 32) | (unsigned)(run + tilesum));
        }
    }
    __syncthreads();
    const int base = sbase;
    if (i < N) {
        int o = base + s[tid] - v;
        off[i] = o;
        cur[i] = o;
    }
    if (i == 0) off[N] = E;
}

__global__ __launch_bounds__(256) void fill_csr_kernel(
    const int* __restrict__ src, const int* __restrict__ dst,
    int* __restrict__ cur, int* __restrict__ csr_src, int E) {
    int e = blockIdx.x * 256 + threadIdx.x;
    if (e >= E) return;
    int d = dst[e];
    int pos = atomicAdd(&cur[d], 1);
    csr_src[pos] = src[e];
}

// ===== Layer 0 fused gather: 2 nodes/wave, 32 lanes/node, 16B/lane, =====
// ===== fully-predicated unroll-4; noise added here (NT load)        =====
__global__ __launch_bounds__(256) void agg0_kernel(
    const int* __restrict__ off, const int* __restrict__ csr_src,
    const unsigned short* __restrict__ h,   // [N,256] bf16
    const float* __restrict__ el,           // [N,4]
    const float* __restrict__ er,
    const float* __restrict__ b0, const float* __restrict__ noise,
    unsigned short* __restrict__ out, int N) {
    int gt = blockIdx.x * 256 + threadIdx.x;
    int n = gt >> 5;                // 32 threads per node
    if (n >= N) return;
    const int lane = gt & 31;
    const int hd = lane >> 3;       // 8 lanes per head
    const int f0 = lane << 3;       // 8 features per lane
    const float ern = er[(size_t)n * 4 + hd];
    const int beg = off[n];
    const int last = off[n + 1] - 1;   // deg >= 1 (self-loop)
    float acc[8] = {0.f, 0.f, 0.f, 0.f, 0.f, 0.f, 0.f, 0.f};
    float l = 0.f;
    for (int p = beg; p <= last; p += 4) {
        int i1 = p + 1, i2 = p + 2, i3 = p + 3;
        const bool v1 = i1 <= last, v2 = i2 <= last, v3 = i3 <= last;
        i1 = v1 ? i1 : last;
        i2 = v2 ? i2 : last;
        i3 = v3 ? i3 : last;
        const int s0 = csr_src[p],  s1 = csr_src[i1];
        const int s2 = csr_src[i2], s3 = csr_src[i3];
        float e0 = el[(size_t)s0 * 4 + hd] + ern;
        float e1 = el[(size_t)s1 * 4 + hd] + ern;
        float e2 = el[(size_t)s2 * 4 + hd] + ern;
        float e3 = el[(size_t)s3 * 4 + hd] + ern;
        const uint4 u0 = *(const uint4*)(h + (size_t)s0 * HD0 + f0);
        const uint4 u1 = *(const uint4*)(h + (size_t)s1 * HD0 + f0);
        const uint4 u2 = *(const uint4*)(h + (size_t)s2 * HD0 + f0);
        const uint4 u3 = *(const uint4*)(h + (size_t)s3 * HD0 + f0);
        e0 = e0 > 0.f ? e0 : 0.2f * e0;
        e1 = e1 > 0.f ? e1 : 0.2f * e1;
        e2 = e2 > 0.f ? e2 : 0.2f * e2;
        e3 = e3 > 0.f ? e3 : 0.2f * e3;
        const float w0 = __expf(e0);
        const float w1 = v1 ? __expf(e1) : 0.f;
        const float w2 = v2 ? __expf(e2) : 0.f;
        const float w3 = v3 ? __expf(e3) : 0.f;
        acc8(acc, u0, w0);
        acc8(acc, u1, w1);
        acc8(acc, u2, w2);
        acc8(acc, u3, w3);
        l += (w0 + w1) + (w2 + w3);
    }
    const float rd = 1.f / l;
    const float4 ba = *(const float4*)(b0 + f0);
    const float4 bb = *(const float4*)(b0 + f0 + 4);
    const f4 na = __builtin_nontemporal_load((const f4*)(noise + (size_t)n * HD0 + f0));
    const f4 nb = __builtin_nontemporal_load((const f4*)(noise + (size_t)n * HD0 + f0 + 4));
    float o[8];
    o[0] = acc[0] * rd + ba.x;
    o[1] = acc[1] * rd + ba.y;
    o[2] = acc[2] * rd + ba.z;
    o[3] = acc[3] * rd + ba.w;
    o[4] = acc[4] * rd + bb.x;
    o[5] = acc[5] * rd + bb.y;
    o[6] = acc[6] * rd + bb.z;
    o[7] = acc[7] * rd + bb.w;
#pragma unroll
    for (int j = 0; j < 8; ++j) o[j] = o[j] > 0.f ? o[j] : 0.01f * o[j];
    o[0] += NOISE_SCALE * na.x;
    o[1] += NOISE_SCALE * na.y;
    o[2] += NOISE_SCALE * na.z;
    o[3] += NOISE_SCALE * na.w;
    o[4] += NOISE_SCALE * nb.x;
    o[5] += NOISE_SCALE * nb.y;
    o[6] += NOISE_SCALE * nb.z;
    o[7] += NOISE_SCALE * nb.w;
    uint4 ov;
    ov.x = (unsigned)f2bf(o[0]) | ((unsigned)f2bf(o[1]) << 16);
    ov.y = (unsigned)f2bf(o[2]) | ((unsigned)f2bf(o[3]) << 16);
    ov.z = (unsigned)f2bf(o[4]) | ((unsigned)f2bf(o[5]) << 16);
    ov.w = (unsigned)f2bf(o[6]) | ((unsigned)f2bf(o[7]) << 16);
    *(uint4*)(out + (size_t)n * HD0 + f0) = ov;
}

// ===== Layer 1 fused gather: 4 nodes/wave, 16 lanes/node, 8B/lane, =====
// ===== fully-predicated unroll-4 + bias -> fp32                    =====
__global__ __launch_bounds__(256) void agg1_kernel(
    const int* __restrict__ off, const int* __restrict__ csr_src,
    const unsigned short* __restrict__ h,   // [N,64] bf16
    const float* __restrict__ el,           // [N]
    const float* __restrict__ er,
    const float* __restrict__ b1, float* __restrict__ out, int N) {
    int gt = blockIdx.x * 256 + threadIdx.x;
    int n = gt >> 4;                // 16 threads per node
    if (n >= N) return;
    const int lane = gt & 15;
    const int f0 = lane << 2;       // 4 features per lane
    const float ern = er[n];
    const int beg = off[n];
    const int last = off[n + 1] - 1;
    float a0 = 0.f, a1 = 0.f, a2 = 0.f, a3 = 0.f, l = 0.f;
    for (int p = beg; p <= last; p += 4) {
        int i1 = p + 1, i2 = p + 2, i3 = p + 3;
        const bool v1 = i1 <= last, v2 = i2 <= last, v3 = i3 <= last;
        i1 = v1 ? i1 : last;
        i2 = v2 ? i2 : last;
        i3 = v3 ? i3 : last;
        const int s0 = csr_src[p],  s1 = csr_src[i1];
        const int s2 = csr_src[i2], s3 = csr_src[i3];
        float e0 = el[s0] + ern;
        float e1 = el[s1] + ern;
        float e2 = el[s2] + ern;
        float e3 = el[s3] + ern;
        const ushort4 u0 = *(const ushort4*)(h + (size_t)s0 * 64 + f0);
        const ushort4 u1 = *(const ushort4*)(h + (size_t)s1 * 64 + f0);
        const ushort4 u2 = *(const ushort4*)(h + (size_t)s2 * 64 + f0);
        const ushort4 u3 = *(const ushort4*)(h + (size_t)s3 * 64 + f0);
        e0 = e0 > 0.f ? e0 : 0.2f * e0;
        e1 = e1 > 0.f ? e1 : 0.2f * e1;
        e2 = e2 > 0.f ? e2 : 0.2f * e2;
        e3 = e3 > 0.f ? e3 : 0.2f * e3;
        const float w0 = __expf(e0);
        const float w1 = v1 ? __expf(e1) : 0.f;
        const float w2 = v2 ? __expf(e2) : 0.f;
        const float w3 = v3 ? __expf(e3) : 0.f;
        a0 += w0 * bf2f(u0.x) + w1 * bf2f(u1.x) + w2 * bf2f(u2.x) + w3 * bf2f(u3.x);
        a1 += w0 * bf2f(u0.y) + w1 * bf2f(u1.y) + w2 * bf2f(u2.y) + w3 * bf2f(u3.y);
        a2 += w0 * bf2f(u0.z) + w1 * bf2f(u1.z) + w2 * bf2f(u2.z) + w3 * bf2f(u3.z);
        a3 += w0 * bf2f(u0.w) + w1 * bf2f(u1.w) + w2 * bf2f(u2.w) + w3 * bf2f(u3.w);
        l += (w0 + w1) + (w2 + w3);
    }
    const float rd = 1.f / l;
    const float4 bv = *(const float4*)(b1 + f0);
    float4 o;
    o.x = a0 * rd + bv.x;
    o.y = a1 * rd + bv.y;
    o.z = a2 * rd + bv.z;
    o.w = a3 * rd + bv.w;
    *(float4*)(out + (size_t)n * 64 + f0) = o;
}

extern "C" void kernel_launch(void* const* d_in, const int* in_sizes, int n_in,
                              void* d_out, int out_size, void* d_ws, size_t ws_size,
                              hipStream_t stream) {
    const float* x     = (const float*)d_in[0];
    const int*   src   = (const int*)d_in[1];
    const int*   dst   = (const int*)d_in[2];
    const float* W0    = (const float*)d_in[3];
    const float* al0   = (const float*)d_in[4];
    const float* ar0   = (const float*)d_in[5];
    const float* b0    = (const float*)d_in[6];
    const float* W1    = (const float*)d_in[7];
    const float* al1   = (const float*)d_in[8];
    const float* ar1   = (const float*)d_in[9];
    const float* b1    = (const float*)d_in[10];
    const float* noise = (const float*)d_in[11];

    const int N = in_sizes[0] / IN_F;   // 100000
    const int E = in_sizes[1];          // 900000
    const int NB = (N + 255) / 256;     // 391 tiles

    // Workspace layout
    char* p = (char*)d_ws;
    unsigned short* h0     = (unsigned short*)p; p += (size_t)N * HD0 * 2;
    unsigned short* agg0b  = (unsigned short*)p; p += (size_t)N * HD0 * 2;
    unsigned short* h1     = (unsigned short*)p; p += (size_t)N * OUT_F * 2;
    unsigned short* W0t    = (unsigned short*)p; p += (size_t)IN_F * HD0 * 2;
    unsigned short* W1t    = (unsigned short*)p; p += (size_t)HD0 * OUT_F * 2;
    float* el     = (float*)p; p += (size_t)N * HEADS * 4;
    float* er     = (float*)p; p += (size_t)N * HEADS * 4;
    int* deg    = (int*)p; p += (size_t)N * 4;
    int* cur    = (int*)p; p += (size_t)N * 4;
    int* off    = (int*)p; p += ((size_t)N + 4) * 4;
    unsigned long long* combo = (unsigned long long*)p; p += 512 * 8;
    int* csr_src= (int*)p; p += (size_t)E * 4;

    // ---------- prep: weights + deg/combo zero ----------
    prep_kernel<<<NB, 256, 0, stream>>>(deg, N, combo, NB, W0, W0t, W1, W1t);

    // ---------- CSR build ----------
    degree_kernel<<<(E + 255) / 256, 256, 0, stream>>>(dst, deg, E);
    scan_fused_kernel<<<NB, 256, 0, stream>>>(deg, off, cur, combo, N, E);
    fill_csr_kernel<<<(E + 255) / 256, 256, 0, stream>>>(src, dst, cur, csr_src, E);

    const int MB = (N + 127) / 128;   // 782

    // ---------- Layer 0 GEMM: x read once, B from L2 ----------
    gemm0_kernel<<<MB, 256, 0, stream>>>(x, W0t, h0, al0, ar0, el, er, N);

    // ---------- Layer 0 aggregate ----------
    agg0_kernel<<<(unsigned)(((size_t)N * 32 + 255) / 256), 256, 0, stream>>>(
        off, csr_src, h0, el, er, b0, noise, agg0b, N);

    // ---------- Layer 1 GEMM ----------
    {
        dim3 grid(OUT_F / 64, MB);  // NT=1
        gemm_fused_kernel<HD0, 1, 1, false><<<grid, 256, 0, stream>>>(
            (const void*)agg0b, W1t, h1, al1, ar1, el, er, N, OUT_F);
    }

    // ---------- Layer 1 aggregate ----------
    agg1_kernel<<<(unsigned)(((size_t)N * 16 + 255) / 256), 256, 0, stream>>>(
        off, csr_src, h1, el, er, b1, (float*)d_out, N);
}

// Round 14
// 457.837 us; speedup vs baseline: 1.0393x; 1.0393x over previous
//
#include <hip/hip_runtime.h>
#include <hip/hip_bf16.h>
#include <math.h>

#define IN_F 128
#define HID 64
#define HEADS 4
#define HD0 (HEADS * HID)   // 256
#define OUT_F 64
#define NOISE_SCALE 2.5372725354060904f

typedef __bf16 bf16x8 __attribute__((ext_vector_type(8)));
typedef float f32x4 __attribute__((ext_vector_type(4)));
typedef float f4 __attribute__((ext_vector_type(4)));
typedef unsigned int u4 __attribute__((ext_vector_type(4)));

__device__ __forceinline__ float bf2f(unsigned short u) {
    return __uint_as_float(((unsigned)u) << 16);
}
__device__ __forceinline__ unsigned short f2bf(float f) {
    unsigned u = __float_as_uint(f);
    u = u + 0x7fffu + ((u >> 16) & 1u);  // round-nearest-even
    return (unsigned short)(u >> 16);
}

// accumulate 8 bf16 features (packed in uint4) scaled by weight
__device__ __forceinline__ void acc8(float* acc, const uint4& u, float wt) {
    acc[0] += wt * __uint_as_float(u.x << 16);
    acc[1] += wt * __uint_as_float(u.x & 0xffff0000u);
    acc[2] += wt * __uint_as_float(u.y << 16);
    acc[3] += wt * __uint_as_float(u.y & 0xffff0000u);
    acc[4] += wt * __uint_as_float(u.z << 16);
    acc[5] += wt * __uint_as_float(u.z & 0xffff0000u);
    acc[6] += wt * __uint_as_float(u.w << 16);
    acc[7] += wt * __uint_as_float(u.w & 0xffff0000u);
}

// pack 8 fp32 -> 8 bf16 (uint4)
__device__ __forceinline__ uint4 pack8(const float4& a, const float4& b) {
    uint4 r;
    r.x = (unsigned)f2bf(a.x) | ((unsigned)f2bf(a.y) << 16);
    r.y = (unsigned)f2bf(a.z) | ((unsigned)f2bf(a.w) << 16);
    r.z = (unsigned)f2bf(b.x) | ((unsigned)f2bf(b.y) << 16);
    r.w = (unsigned)f2bf(b.z) | ((unsigned)f2bf(b.w) << 16);
    return r;
}

// ---------- prep: W0/W1 transpose-cast + zero deg + zero scan flags ----------
__global__ __launch_bounds__(256) void prep_kernel(
    int* __restrict__ deg, int N,
    unsigned long long* __restrict__ combo, int ntiles,
    const float* __restrict__ W0, unsigned short* __restrict__ W0t,
    const float* __restrict__ W1, unsigned short* __restrict__ W1t) {
    const int b = blockIdx.x;
    int i = b * 256 + threadIdx.x;
    if (i < N) deg[i] = 0;
    if (i < ntiles) combo[i] = 0ULL;
    if (b < (IN_F * HD0) / 256) {            // 128 blocks
        int n = i / IN_F, k = i % IN_F;
        W0t[i] = f2bf(W0[(size_t)k * HD0 + n]);
    } else if (b < (IN_F * HD0) / 256 + (HD0 * OUT_F) / 256) {  // next 64
        int j = i - IN_F * HD0;
        int n = j / HD0, k = j % HD0;
        W1t[j] = f2bf(W1[(size_t)k * OUT_F + n]);
    }
}

// ---------- Layer-0 GEMM: single-barrier, NT=1 per block ----------
// Full A-tile (128x128 fp32->bf16, 34.3KB) + one 64-col B-tile (17.2KB) in LDS,
// ONE sync, then 32 MFMAs pure-LDS, LDS-restage coalesced C.
// acc[2][4]=32 regs (no occupancy cliff); 51.5KB LDS -> 3 blocks/CU.
__global__ __launch_bounds__(256) void gemm0_kernel(
    const float* __restrict__ x, const unsigned short* __restrict__ Bt,
    unsigned short* __restrict__ C, const float* __restrict__ al,
    const float* __restrict__ ar, float* __restrict__ el,
    float* __restrict__ er, int M) {
    constexpr int K = IN_F;          // 128
    constexpr int ASTR = 134;        // 67 dwords (odd) -> <=2-way conflicts
    constexpr int BSTR = 134;
    constexpr int CSTR = 66;         // 33 dwords (odd)
    __shared__ __align__(16) unsigned short As[128 * ASTR];   // 34.3 KB
    __shared__ __align__(16) unsigned short Bs[64 * BSTR];    // 17.2 KB
    const int tid = threadIdx.x;
    const int lane = tid & 63, w = tid >> 6;
    const int q = lane >> 4, c = lane & 15;
    const int row0 = blockIdx.y * 128;
    const int n0 = blockIdx.x * 64;
    const int head = blockIdx.x;
    // ---- stage full A tile (fp32 -> bf16) ----
    {
        const int r_st = tid >> 1, hh = tid & 1;
        const int gr = row0 + r_st;
        const float* xp = x + (size_t)gr * K + hh * 16;
        unsigned short* ap = As + r_st * ASTR + hh * 16;
#pragma unroll
        for (int k0 = 0; k0 < K; k0 += 32) {
            uint4 av0 = make_uint4(0, 0, 0, 0), av1 = make_uint4(0, 0, 0, 0);
            if (gr < M) {
                const float4 fa = *(const float4*)(xp + k0);
                const float4 fb = *(const float4*)(xp + k0 + 4);
                const float4 fc = *(const float4*)(xp + k0 + 8);
                const float4 fd = *(const float4*)(xp + k0 + 12);
                av0 = pack8(fa, fb);
                av1 = pack8(fc, fd);
            }
            *(uint4*)(ap + k0) = av0;
            *(uint4*)(ap + k0 + 8) = av1;
        }
    }
    // ---- stage B tile (64 rows x 128 cols bf16) ----
    for (int i = tid; i < 64 * 16; i += 256) {
        int n = i >> 4, kc = i & 15;
        *(uint4*)(Bs + n * BSTR + kc * 8) =
            *(const uint4*)(Bt + (size_t)(n0 + n) * K + kc * 8);
    }
    __syncthreads();
    // ---- MFMA main loop: pure LDS, no barriers ----
    f32x4 acc[2][4] = {};
#pragma unroll
    for (int k0 = 0; k0 < K; k0 += 32) {
        const bf16x8 af0 = *(const bf16x8*)(As + (w * 32 + c) * ASTR + k0 + q * 8);
        const bf16x8 af1 = *(const bf16x8*)(As + (w * 32 + 16 + c) * ASTR + k0 + q * 8);
#pragma unroll
        for (int nt = 0; nt < 4; ++nt) {
            const bf16x8 bfr = *(const bf16x8*)(Bs + (nt * 16 + c) * BSTR + k0 + q * 8);
            acc[0][nt] = __builtin_amdgcn_mfma_f32_16x16x32_bf16(
                af0, bfr, acc[0][nt], 0, 0, 0);
            acc[1][nt] = __builtin_amdgcn_mfma_f32_16x16x32_bf16(
                af1, bfr, acc[1][nt], 0, 0, 0);
        }
    }
    // ---- epilogue: el/er + C restage into Bs (free now) ----
    float alv[4], arv[4];
#pragma unroll
    for (int nt = 0; nt < 4; ++nt) {
        alv[nt] = al[n0 + nt * 16 + c];
        arv[nt] = ar[n0 + nt * 16 + c];
    }
    __syncthreads();   // everyone done reading Bs
    unsigned short* Cs = Bs;   // 128*CSTR*2 = 16.9KB <= 17.2KB
#pragma unroll
    for (int mt = 0; mt < 2; ++mt) {
#pragma unroll
        for (int r = 0; r < 4; ++r) {
            const int row = w * 32 + mt * 16 + q * 4 + r;
            const int grow = row0 + row;
            const bool ok = grow < M;
            float elp = 0.f, erp = 0.f;
#pragma unroll
            for (int nt = 0; nt < 4; ++nt) {
                float v = acc[mt][nt][r];
                elp += v * alv[nt];
                erp += v * arv[nt];
                Cs[row * CSTR + nt * 16 + c] = f2bf(v);
            }
#pragma unroll
            for (int o = 8; o > 0; o >>= 1) {
                elp += __shfl_down(elp, o, 16);
                erp += __shfl_down(erp, o, 16);
            }
            if (c == 0 && ok) {
                el[(size_t)grow * HEADS + head] = elp;
                er[(size_t)grow * HEADS + head] = erp;
            }
        }
    }
    __syncthreads();
    // coalesced writeout: 8 threads cover one row's 64 cols (128B)
    for (int i = tid; i < 128 * 8; i += 256) {
        int row = i >> 3, ch = i & 7;
        int grow = row0 + row;
        if (grow < M)
            *(uint4*)(C + (size_t)grow * HD0 + n0 + ch * 8) =
                *(const uint4*)(Cs + row * CSTR + ch * 8);
    }
}

// ---------- generic MFMA GEMM + fused el/er (layer 1, NT=1) ----------
template <int K, int H, int NT, bool CVT>
__global__ __launch_bounds__(256) void gemm_fused_kernel(
    const void* __restrict__ Asrc, const unsigned short* __restrict__ Bt,
    unsigned short* __restrict__ C, const float* __restrict__ al,
    const float* __restrict__ ar, float* __restrict__ el,
    float* __restrict__ er, int M, int NC) {
    constexpr int BSTR = K + 8;
    constexpr int ASTR = 40;
    constexpr int NROWS = 64 * NT;
    constexpr int CSTR = NROWS + 8;
    __shared__ __align__(16) unsigned short Bs[NROWS * BSTR];
    __shared__ __align__(16) unsigned short As[128 * ASTR];
    const unsigned short* Ab = (const unsigned short*)Asrc;
    const float* Af = (const float*)Asrc;
    const int tid = threadIdx.x;
    const int lane = tid & 63, w = tid >> 6;
    const int row0 = blockIdx.y * 128;
    const int n0 = blockIdx.x * NROWS;
    for (int i = tid; i < NROWS * (K / 8); i += 256) {
        int n = i / (K / 8), kc = i % (K / 8);
        *(uint4*)(Bs + n * BSTR + kc * 8) =
            *(const uint4*)(Bt + (size_t)(n0 + n) * K + kc * 8);
    }
    f32x4 acc[2][4 * NT] = {};
    const int q = lane >> 4, c = lane & 15;
    const int r_st = tid >> 1, hh = tid & 1;
    for (int k0 = 0; k0 < K; k0 += 32) {
        int gr = row0 + r_st;
        uint4 av0 = make_uint4(0, 0, 0, 0), av1 = make_uint4(0, 0, 0, 0);
        if (gr < M) {
            if (CVT) {
                const float* xp = Af + (size_t)gr * K + k0 + hh * 16;
                const float4 fa = *(const float4*)xp;
                const float4 fb = *(const float4*)(xp + 4);
                const float4 fc = *(const float4*)(xp + 8);
                const float4 fd = *(const float4*)(xp + 12);
                av0 = pack8(fa, fb);
                av1 = pack8(fc, fd);
            } else {
                const unsigned short* ap = Ab + (size_t)gr * K + k0 + hh * 16;
                av0 = *(const uint4*)(ap);
                av1 = *(const uint4*)(ap + 8);
            }
        }
        __syncthreads();
        *(uint4*)(As + r_st * ASTR + hh * 16) = av0;
        *(uint4*)(As + r_st * ASTR + hh * 16 + 8) = av1;
        __syncthreads();
        bf16x8 af[2], bfr[4 * NT];
        af[0] = *(const bf16x8*)(As + (w * 32 + c) * ASTR + q * 8);
        af[1] = *(const bf16x8*)(As + (w * 32 + 16 + c) * ASTR + q * 8);
#pragma unroll
        for (int nt = 0; nt < 4 * NT; ++nt)
            bfr[nt] = *(const bf16x8*)(Bs + (nt * 16 + c) * BSTR + k0 + q * 8);
#pragma unroll
        for (int mt = 0; mt < 2; ++mt)
#pragma unroll
            for (int nt = 0; nt < 4 * NT; ++nt)
                acc[mt][nt] = __builtin_amdgcn_mfma_f32_16x16x32_bf16(
                    af[mt], bfr[nt], acc[mt][nt], 0, 0, 0);
    }
    float alv[4 * NT], arv[4 * NT];
#pragma unroll
    for (int nt = 0; nt < 4 * NT; ++nt) {
        alv[nt] = al[n0 + nt * 16 + c];
        arv[nt] = ar[n0 + nt * 16 + c];
    }
    __syncthreads();
    unsigned short* Cs = Bs;
    const int headbase = n0 >> 6;
#pragma unroll
    for (int mt = 0; mt < 2; ++mt) {
#pragma unroll
        for (int r = 0; r < 4; ++r) {
            const int row = w * 32 + mt * 16 + q * 4 + r;
            const int grow = row0 + row;
            const bool ok = grow < M;
#pragma unroll
            for (int g = 0; g < NT; ++g) {
                float elp = 0.f, erp = 0.f;
#pragma unroll
                for (int t = 0; t < 4; ++t) {
                    int nt = g * 4 + t;
                    float v = acc[mt][nt][r];
                    elp += v * alv[nt];
                    erp += v * arv[nt];
                    Cs[row * CSTR + nt * 16 + c] = f2bf(v);
                }
#pragma unroll
                for (int o = 8; o > 0; o >>= 1) {
                    elp += __shfl_down(elp, o, 16);
                    erp += __shfl_down(erp, o, 16);
                }
                if (c == 0 && ok) {
                    el[(size_t)grow * H + headbase + g] = elp;
                    er[(size_t)grow * H + headbase + g] = erp;
                }
            }
        }
    }
    __syncthreads();
    constexpr int CPR = NROWS / 8;
    for (int i = tid; i < 128 * CPR; i += 256) {
        int row = i / CPR, ch = i % CPR;
        int grow = row0 + row;
        if (grow < M)
            *(uint4*)(C + (size_t)grow * NC + n0 + ch * 8) =
                *(const uint4*)(Cs + row * CSTR + ch * 8);
    }
}

// ================= CSR build =================
__global__ __launch_bounds__(256) void degree_kernel(
    const int* __restrict__ dst, int* __restrict__ deg, int E) {
    int e = blockIdx.x * 256 + threadIdx.x;
    if (e < E) atomicAdd(&deg[dst[e]], 1);
}

// single-pass scan with decoupled lookback
__global__ __launch_bounds__(256) void scan_fused_kernel(
    const int* __restrict__ deg, int* __restrict__ off, int* __restrict__ cur,
    unsigned long long* __restrict__ combo, int N, int E) {
    const int t = blockIdx.x;
    __shared__ int s[256];
    __shared__ int sbase;
    const int tid = threadIdx.x;
    const int i = t * 256 + tid;
    const int v = (i < N) ? deg[i] : 0;
    s[tid] = v;
    __syncthreads();
    for (int d = 1; d < 256; d <<= 1) {
        int tt = (tid >= d) ? s[tid - d] : 0;
        __syncthreads();
        s[tid] += tt;
        __syncthreads();
    }
    const int tilesum = s[255];
    if (tid == 0) {
        if (t == 0) {
            atomicExch(&combo[0], (2ULL << 32) | (unsigned)tilesum);
            sbase = 0;
        } else {
            atomicExch(&combo[t], (1ULL << 32) | (unsigned)tilesum);
            int run = 0;
            int j = t - 1;
            while (true) {
                unsigned long long c;
                do {
                    c = atomicAdd(&combo[j], 0ULL);
                } while ((c >> 32) == 0ULL);
                run += (int)(c & 0xffffffffULL);
                if ((c >> 32) == 2ULL) break;
                --j;
            }
            sbase = run;
            atomicExch(&combo[t], (2ULL << 32) | (unsigned)(run + tilesum));
        }
    }
    __syncthreads();
    const int base = sbase;
    if (i < N) {
        int o = base + s[tid] - v;
        off[i] = o;
        cur[i] = o;
    }
    if (i == 0) off[N] = E;
}

__global__ __launch_bounds__(256) void fill_csr_kernel(
    const int* __restrict__ src, const int* __restrict__ dst,
    int* __restrict__ cur, int* __restrict__ csr_src, int E) {
    int e = blockIdx.x * 256 + threadIdx.x;
    if (e >= E) return;
    int d = dst[e];
    int pos = atomicAdd(&cur[d], 1);
    csr_src[pos] = src[e];
}

// ===== Layer 0 fused gather: 2 nodes/wave, 32 lanes/node, 16B/lane, =====
// ===== fully-predicated unroll-4; noise added here (NT load)        =====
__global__ __launch_bounds__(256) void agg0_kernel(
    const int* __restrict__ off, const int* __restrict__ csr_src,
    const unsigned short* __restrict__ h,   // [N,256] bf16
    const float* __restrict__ el,           // [N,4]
    const float* __restrict__ er,
    const float* __restrict__ b0, const float* __restrict__ noise,
    unsigned short* __restrict__ out, int N) {
    int gt = blockIdx.x * 256 + threadIdx.x;
    int n = gt >> 5;                // 32 threads per node
    if (n >= N) return;
    const int lane = gt & 31;
    const int hd = lane >> 3;       // 8 lanes per head
    const int f0 = lane << 3;       // 8 features per lane
    const float ern = er[(size_t)n * 4 + hd];
    const int beg = off[n];
    const int last = off[n + 1] - 1;   // deg >= 1 (self-loop)
    float acc[8] = {0.f, 0.f, 0.f, 0.f, 0.f, 0.f, 0.f, 0.f};
    float l = 0.f;
    for (int p = beg; p <= last; p += 4) {
        int i1 = p + 1, i2 = p + 2, i3 = p + 3;
        const bool v1 = i1 <= last, v2 = i2 <= last, v3 = i3 <= last;
        i1 = v1 ? i1 : last;
        i2 = v2 ? i2 : last;
        i3 = v3 ? i3 : last;
        const int s0 = csr_src[p],  s1 = csr_src[i1];
        const int s2 = csr_src[i2], s3 = csr_src[i3];
        float e0 = el[(size_t)s0 * 4 + hd] + ern;
        float e1 = el[(size_t)s1 * 4 + hd] + ern;
        float e2 = el[(size_t)s2 * 4 + hd] + ern;
        float e3 = el[(size_t)s3 * 4 + hd] + ern;
        const uint4 u0 = *(const uint4*)(h + (size_t)s0 * HD0 + f0);
        const uint4 u1 = *(const uint4*)(h + (size_t)s1 * HD0 + f0);
        const uint4 u2 = *(const uint4*)(h + (size_t)s2 * HD0 + f0);
        const uint4 u3 = *(const uint4*)(h + (size_t)s3 * HD0 + f0);
        e0 = e0 > 0.f ? e0 : 0.2f * e0;
        e1 = e1 > 0.f ? e1 : 0.2f * e1;
        e2 = e2 > 0.f ? e2 : 0.2f * e2;
        e3 = e3 > 0.f ? e3 : 0.2f * e3;
        const float w0 = __expf(e0);
        const float w1 = v1 ? __expf(e1) : 0.f;
        const float w2 = v2 ? __expf(e2) : 0.f;
        const float w3 = v3 ? __expf(e3) : 0.f;
        acc8(acc, u0, w0);
        acc8(acc, u1, w1);
        acc8(acc, u2, w2);
        acc8(acc, u3, w3);
        l += (w0 + w1) + (w2 + w3);
    }
    const float rd = 1.f / l;
    const float4 ba = *(const float4*)(b0 + f0);
    const float4 bb = *(const float4*)(b0 + f0 + 4);
    const f4 na = __builtin_nontemporal_load((const f4*)(noise + (size_t)n * HD0 + f0));
    const f4 nb = __builtin_nontemporal_load((const f4*)(noise + (size_t)n * HD0 + f0 + 4));
    float o[8];
    o[0] = acc[0] * rd + ba.x;
    o[1] = acc[1] * rd + ba.y;
    o[2] = acc[2] * rd + ba.z;
    o[3] = acc[3] * rd + ba.w;
    o[4] = acc[4] * rd + bb.x;
    o[5] = acc[5] * rd + bb.y;
    o[6] = acc[6] * rd + bb.z;
    o[7] = acc[7] * rd + bb.w;
#pragma unroll
    for (int j = 0; j < 8; ++j) o[j] = o[j] > 0.f ? o[j] : 0.01f * o[j];
    o[0] += NOISE_SCALE * na.x;
    o[1] += NOISE_SCALE * na.y;
    o[2] += NOISE_SCALE * na.z;
    o[3] += NOISE_SCALE * na.w;
    o[4] += NOISE_SCALE * nb.x;
    o[5] += NOISE_SCALE * nb.y;
    o[6] += NOISE_SCALE * nb.z;
    o[7] += NOISE_SCALE * nb.w;
    uint4 ov;
    ov.x = (unsigned)f2bf(o[0]) | ((unsigned)f2bf(o[1]) << 16);
    ov.y = (unsigned)f2bf(o[2]) | ((unsigned)f2bf(o[3]) << 16);
    ov.z = (unsigned)f2bf(o[4]) | ((unsigned)f2bf(o[5]) << 16);
    ov.w = (unsigned)f2bf(o[6]) | ((unsigned)f2bf(o[7]) << 16);
    *(uint4*)(out + (size_t)n * HD0 + f0) = ov;
}

// ===== Layer 1 fused gather: 4 nodes/wave, 16 lanes/node, 8B/lane, =====
// ===== fully-predicated unroll-4 + bias -> fp32                    =====
__global__ __launch_bounds__(256) void agg1_kernel(
    const int* __restrict__ off, const int* __restrict__ csr_src,
    const unsigned short* __restrict__ h,   // [N,64] bf16
    const float* __restrict__ el,           // [N]
    const float* __restrict__ er,
    const float* __restrict__ b1, float* __restrict__ out, int N) {
    int gt = blockIdx.x * 256 + threadIdx.x;
    int n = gt >> 4;                // 16 threads per node
    if (n >= N) return;
    const int lane = gt & 15;
    const int f0 = lane << 2;       // 4 features per lane
    const float ern = er[n];
    const int beg = off[n];
    const int last = off[n + 1] - 1;
    float a0 = 0.f, a1 = 0.f, a2 = 0.f, a3 = 0.f, l = 0.f;
    for (int p = beg; p <= last; p += 4) {
        int i1 = p + 1, i2 = p + 2, i3 = p + 3;
        const bool v1 = i1 <= last, v2 = i2 <= last, v3 = i3 <= last;
        i1 = v1 ? i1 : last;
        i2 = v2 ? i2 : last;
        i3 = v3 ? i3 : last;
        const int s0 = csr_src[p],  s1 = csr_src[i1];
        const int s2 = csr_src[i2], s3 = csr_src[i3];
        float e0 = el[s0] + ern;
        float e1 = el[s1] + ern;
        float e2 = el[s2] + ern;
        float e3 = el[s3] + ern;
        const ushort4 u0 = *(const ushort4*)(h + (size_t)s0 * 64 + f0);
        const ushort4 u1 = *(const ushort4*)(h + (size_t)s1 * 64 + f0);
        const ushort4 u2 = *(const ushort4*)(h + (size_t)s2 * 64 + f0);
        const ushort4 u3 = *(const ushort4*)(h + (size_t)s3 * 64 + f0);
        e0 = e0 > 0.f ? e0 : 0.2f * e0;
        e1 = e1 > 0.f ? e1 : 0.2f * e1;
        e2 = e2 > 0.f ? e2 : 0.2f * e2;
        e3 = e3 > 0.f ? e3 : 0.2f * e3;
        const float w0 = __expf(e0);
        const float w1 = v1 ? __expf(e1) : 0.f;
        const float w2 = v2 ? __expf(e2) : 0.f;
        const float w3 = v3 ? __expf(e3) : 0.f;
        a0 += w0 * bf2f(u0.x) + w1 * bf2f(u1.x) + w2 * bf2f(u2.x) + w3 * bf2f(u3.x);
        a1 += w0 * bf2f(u0.y) + w1 * bf2f(u1.y) + w2 * bf2f(u2.y) + w3 * bf2f(u3.y);
        a2 += w0 * bf2f(u0.z) + w1 * bf2f(u1.z) + w2 * bf2f(u2.z) + w3 * bf2f(u3.z);
        a3 += w0 * bf2f(u0.w) + w1 * bf2f(u1.w) + w2 * bf2f(u2.w) + w3 * bf2f(u3.w);
        l += (w0 + w1) + (w2 + w3);
    }
    const float rd = 1.f / l;
    const float4 bv = *(const float4*)(b1 + f0);
    float4 o;
    o.x = a0 * rd + bv.x;
    o.y = a1 * rd + bv.y;
    o.z = a2 * rd + bv.z;
    o.w = a3 * rd + bv.w;
    *(float4*)(out + (size_t)n * 64 + f0) = o;
}

extern "C" void kernel_launch(void* const* d_in, const int* in_sizes, int n_in,
                              void* d_out, int out_size, void* d_ws, size_t ws_size,
                              hipStream_t stream) {
    const float* x     = (const float*)d_in[0];
    const int*   src   = (const int*)d_in[1];
    const int*   dst   = (const int*)d_in[2];
    const float* W0    = (const float*)d_in[3];
    const float* al0   = (const float*)d_in[4];
    const float* ar0   = (const float*)d_in[5];
    const float* b0    = (const float*)d_in[6];
    const float* W1    = (const float*)d_in[7];
    const float* al1   = (const float*)d_in[8];
    const float* ar1   = (const float*)d_in[9];
    const float* b1    = (const float*)d_in[10];
    const float* noise = (const float*)d_in[11];

    const int N = in_sizes[0] / IN_F;   // 100000
    const int E = in_sizes[1];          // 900000
    const int NB = (N + 255) / 256;     // 391 tiles

    // Workspace layout
    char* p = (char*)d_ws;
    unsigned short* h0     = (unsigned short*)p; p += (size_t)N * HD0 * 2;
    unsigned short* agg0b  = (unsigned short*)p; p += (size_t)N * HD0 * 2;
    unsigned short* h1     = (unsigned short*)p; p += (size_t)N * OUT_F * 2;
    unsigned short* W0t    = (unsigned short*)p; p += (size_t)IN_F * HD0 * 2;
    unsigned short* W1t    = (unsigned short*)p; p += (size_t)HD0 * OUT_F * 2;
    float* el     = (float*)p; p += (size_t)N * HEADS * 4;
    float* er     = (float*)p; p += (size_t)N * HEADS * 4;
    int* deg    = (int*)p; p += (size_t)N * 4;
    int* cur    = (int*)p; p += (size_t)N * 4;
    int* off    = (int*)p; p += ((size_t)N + 4) * 4;
    unsigned long long* combo = (unsigned long long*)p; p += 512 * 8;
    int* csr_src= (int*)p; p += (size_t)E * 4;

    // ---------- prep: weights + deg/combo zero ----------
    prep_kernel<<<NB, 256, 0, stream>>>(deg, N, combo, NB, W0, W0t, W1, W1t);

    // ---------- CSR build ----------
    degree_kernel<<<(E + 255) / 256, 256, 0, stream>>>(dst, deg, E);
    scan_fused_kernel<<<NB, 256, 0, stream>>>(deg, off, cur, combo, N, E);
    fill_csr_kernel<<<(E + 255) / 256, 256, 0, stream>>>(src, dst, cur, csr_src, E);

    const int MB = (N + 127) / 128;   // 782

    // ---------- Layer 0 GEMM: single-barrier, 4 head-blocks ----------
    {
        dim3 grid(HD0 / 64, MB);   // (4, 782)
        gemm0_kernel<<<grid, 256, 0, stream>>>(x, W0t, h0, al0, ar0, el, er, N);
    }

    // ---------- Layer 0 aggregate ----------
    agg0_kernel<<<(unsigned)(((size_t)N * 32 + 255) / 256), 256, 0, stream>>>(
        off, csr_src, h0, el, er, b0, noise, agg0b, N);

    // ---------- Layer 1 GEMM ----------
    {
        dim3 grid(OUT_F / 64, MB);  // NT=1
        gemm_fused_kernel<HD0, 1, 1, false><<<grid, 256, 0, stream>>>(
            (const void*)agg0b, W1t, h1, al1, ar1, el, er, N, OUT_F);
    }

    // ---------- Layer 1 aggregate ----------
    agg1_kernel<<<(unsigned)(((size_t)N * 16 + 255) / 256), 256, 0, stream>>>(
        off, csr_src, h1, el, er, b1, (float*)d_out, N);
}

// Round 15
// 430.697 us; speedup vs baseline: 1.1048x; 1.0630x over previous
//
#include <hip/hip_runtime.h>
#include <hip/hip_bf16.h>
#include <math.h>

#define IN_F 128
#define HID 64
#define HEADS 4
#define HD0 (HEADS * HID)   // 256
#define OUT_F 64
#define NOISE_SCALE 2.5372725354060904f

typedef __bf16 bf16x8 __attribute__((ext_vector_type(8)));
typedef float f32x4 __attribute__((ext_vector_type(4)));
typedef float f4 __attribute__((ext_vector_type(4)));
typedef unsigned int u4 __attribute__((ext_vector_type(4)));

__device__ __forceinline__ float bf2f(unsigned short u) {
    return __uint_as_float(((unsigned)u) << 16);
}
__device__ __forceinline__ unsigned short f2bf(float f) {
    unsigned u = __float_as_uint(f);
    u = u + 0x7fffu + ((u >> 16) & 1u);  // round-nearest-even
    return (unsigned short)(u >> 16);
}

// accumulate 8 bf16 features (packed in uint4) scaled by weight
__device__ __forceinline__ void acc8(float* acc, const uint4& u, float wt) {
    acc[0] += wt * __uint_as_float(u.x << 16);
    acc[1] += wt * __uint_as_float(u.x & 0xffff0000u);
    acc[2] += wt * __uint_as_float(u.y << 16);
    acc[3] += wt * __uint_as_float(u.y & 0xffff0000u);
    acc[4] += wt * __uint_as_float(u.z << 16);
    acc[5] += wt * __uint_as_float(u.z & 0xffff0000u);
    acc[6] += wt * __uint_as_float(u.w << 16);
    acc[7] += wt * __uint_as_float(u.w & 0xffff0000u);
}

// pack 8 fp32 -> 8 bf16 (uint4)
__device__ __forceinline__ uint4 pack8(const float4& a, const float4& b) {
    uint4 r;
    r.x = (unsigned)f2bf(a.x) | ((unsigned)f2bf(a.y) << 16);
    r.y = (unsigned)f2bf(a.z) | ((unsigned)f2bf(a.w) << 16);
    r.z = (unsigned)f2bf(b.x) | ((unsigned)f2bf(b.y) << 16);
    r.w = (unsigned)f2bf(b.z) | ((unsigned)f2bf(b.w) << 16);
    return r;
}

// ---------- prep: W0/W1 transpose-cast + zero deg ----------
__global__ __launch_bounds__(256) void prep_kernel(
    int* __restrict__ deg, int N,
    const float* __restrict__ W0, unsigned short* __restrict__ W0t,
    const float* __restrict__ W1, unsigned short* __restrict__ W1t) {
    const int b = blockIdx.x;
    int i = b * 256 + threadIdx.x;
    if (i < N) deg[i] = 0;
    if (b < (IN_F * HD0) / 256) {            // 128 blocks
        int n = i / IN_F, k = i % IN_F;
        W0t[i] = f2bf(W0[(size_t)k * HD0 + n]);
    } else if (b < (IN_F * HD0) / 256 + (HD0 * OUT_F) / 256) {  // next 64
        int j = i - IN_F * HD0;
        int n = j / HD0, k = j % HD0;
        W1t[j] = f2bf(W1[(size_t)k * OUT_F + n]);
    }
}

// ---------- MFMA GEMM + fused el/er epilogue, NT n-groups of 64 ----------
// CVT: A source is fp32, convert to bf16 during staging (layer-0 path)
// C written via LDS restage -> coalesced uint4 stores
template <int K, int H, int NT, bool CVT>
__global__ __launch_bounds__(256) void gemm_fused_kernel(
    const void* __restrict__ Asrc, const unsigned short* __restrict__ Bt,
    unsigned short* __restrict__ C, const float* __restrict__ al,
    const float* __restrict__ ar, float* __restrict__ el,
    float* __restrict__ er, int M, int NC) {
    constexpr int BSTR = K + 8;
    constexpr int ASTR = 40;
    constexpr int NROWS = 64 * NT;
    constexpr int CSTR = NROWS + 8;
    __shared__ __align__(16) unsigned short Bs[NROWS * BSTR];
    __shared__ __align__(16) unsigned short As[128 * ASTR];
    const unsigned short* Ab = (const unsigned short*)Asrc;
    const float* Af = (const float*)Asrc;
    const int tid = threadIdx.x;
    const int lane = tid & 63, w = tid >> 6;
    const int row0 = blockIdx.y * 128;
    const int n0 = blockIdx.x * NROWS;
    for (int i = tid; i < NROWS * (K / 8); i += 256) {
        int n = i / (K / 8), kc = i % (K / 8);
        *(uint4*)(Bs + n * BSTR + kc * 8) =
            *(const uint4*)(Bt + (size_t)(n0 + n) * K + kc * 8);
    }
    f32x4 acc[2][4 * NT] = {};
    const int q = lane >> 4, c = lane & 15;
    const int r_st = tid >> 1, hh = tid & 1;
    for (int k0 = 0; k0 < K; k0 += 32) {
        int gr = row0 + r_st;
        uint4 av0 = make_uint4(0, 0, 0, 0), av1 = make_uint4(0, 0, 0, 0);
        if (gr < M) {
            if (CVT) {
                const float* xp = Af + (size_t)gr * K + k0 + hh * 16;
                const float4 fa = *(const float4*)xp;
                const float4 fb = *(const float4*)(xp + 4);
                const float4 fc = *(const float4*)(xp + 8);
                const float4 fd = *(const float4*)(xp + 12);
                av0 = pack8(fa, fb);
                av1 = pack8(fc, fd);
            } else {
                const unsigned short* ap = Ab + (size_t)gr * K + k0 + hh * 16;
                av0 = *(const uint4*)(ap);
                av1 = *(const uint4*)(ap + 8);
            }
        }
        __syncthreads();
        *(uint4*)(As + r_st * ASTR + hh * 16) = av0;
        *(uint4*)(As + r_st * ASTR + hh * 16 + 8) = av1;
        __syncthreads();
        bf16x8 af[2], bfr[4 * NT];
        af[0] = *(const bf16x8*)(As + (w * 32 + c) * ASTR + q * 8);
        af[1] = *(const bf16x8*)(As + (w * 32 + 16 + c) * ASTR + q * 8);
#pragma unroll
        for (int nt = 0; nt < 4 * NT; ++nt)
            bfr[nt] = *(const bf16x8*)(Bs + (nt * 16 + c) * BSTR + k0 + q * 8);
#pragma unroll
        for (int mt = 0; mt < 2; ++mt)
#pragma unroll
            for (int nt = 0; nt < 4 * NT; ++nt)
                acc[mt][nt] = __builtin_amdgcn_mfma_f32_16x16x32_bf16(
                    af[mt], bfr[nt], acc[mt][nt], 0, 0, 0);
    }
    float alv[4 * NT], arv[4 * NT];
#pragma unroll
    for (int nt = 0; nt < 4 * NT; ++nt) {
        alv[nt] = al[n0 + nt * 16 + c];
        arv[nt] = ar[n0 + nt * 16 + c];
    }
    // Bs consumed by all waves; reuse as C-restage buffer
    __syncthreads();
    unsigned short* Cs = Bs;   // needs 128*CSTR <= NROWS*BSTR (holds for NT=1,2)
    const int headbase = n0 >> 6;
#pragma unroll
    for (int mt = 0; mt < 2; ++mt) {
#pragma unroll
        for (int r = 0; r < 4; ++r) {
            const int row = w * 32 + mt * 16 + q * 4 + r;
            const int grow = row0 + row;
            const bool ok = grow < M;
#pragma unroll
            for (int g = 0; g < NT; ++g) {
                float elp = 0.f, erp = 0.f;
#pragma unroll
                for (int t = 0; t < 4; ++t) {
                    int nt = g * 4 + t;
                    float v = acc[mt][nt][r];
                    elp += v * alv[nt];
                    erp += v * arv[nt];
                    Cs[row * CSTR + nt * 16 + c] = f2bf(v);
                }
#pragma unroll
                for (int o = 8; o > 0; o >>= 1) {
                    elp += __shfl_down(elp, o, 16);
                    erp += __shfl_down(erp, o, 16);
                }
                if (c == 0 && ok) {
                    el[(size_t)grow * H + headbase + g] = elp;
                    er[(size_t)grow * H + headbase + g] = erp;
                }
            }
        }
    }
    __syncthreads();
    // coalesced writeout: NROWS bf16 per row = NROWS/8 uint4 chunks
    constexpr int CPR = NROWS / 8;
    for (int i = tid; i < 128 * CPR; i += 256) {
        int row = i / CPR, ch = i % CPR;
        int grow = row0 + row;
        if (grow < M)
            *(uint4*)(C + (size_t)grow * NC + n0 + ch * 8) =
                *(const uint4*)(Cs + row * CSTR + ch * 8);
    }
}

// ================= CSR build =================
__global__ __launch_bounds__(256) void degree_kernel(
    const int* __restrict__ dst, int* __restrict__ deg, int E) {
    int e = blockIdx.x * 256 + threadIdx.x;
    if (e < E) atomicAdd(&deg[dst[e]], 1);
}

__global__ __launch_bounds__(256) void scan_block_kernel(
    const int* __restrict__ deg, int* __restrict__ off,
    int* __restrict__ bsum, int N) {
    __shared__ int s[256];
    int i = blockIdx.x * 256 + threadIdx.x;
    int v = (i < N) ? deg[i] : 0;
    s[threadIdx.x] = v;
    __syncthreads();
    for (int d = 1; d < 256; d <<= 1) {
        int t = (threadIdx.x >= d) ? s[threadIdx.x - d] : 0;
        __syncthreads();
        s[threadIdx.x] += t;
        __syncthreads();
    }
    if (i < N) off[i] = s[threadIdx.x] - v;
    if (threadIdx.x == 255) bsum[blockIdx.x] = s[255];
}

__global__ __launch_bounds__(512) void scan_partials_kernel(int* __restrict__ bsum, int nb) {
    __shared__ int s[512];
    int v = (threadIdx.x < nb) ? bsum[threadIdx.x] : 0;
    s[threadIdx.x] = v;
    __syncthreads();
    for (int d = 1; d < 512; d <<= 1) {
        int t = (threadIdx.x >= d) ? s[threadIdx.x - d] : 0;
        __syncthreads();
        s[threadIdx.x] += t;
        __syncthreads();
    }
    if (threadIdx.x < nb) bsum[threadIdx.x] = s[threadIdx.x] - v;
}

__global__ __launch_bounds__(256) void add_offsets_kernel(
    int* __restrict__ off, int* __restrict__ cur,
    const int* __restrict__ bsum, int N, int E) {
    int i = blockIdx.x * 256 + threadIdx.x;
    if (i < N) {
        int v = off[i] + bsum[blockIdx.x];
        off[i] = v;
        cur[i] = v;
    }
    if (i == 0) off[N] = E;
}

__global__ __launch_bounds__(256) void fill_csr_kernel(
    const int* __restrict__ src, const int* __restrict__ dst,
    int* __restrict__ cur, int* __restrict__ csr_src, int E) {
    int e = blockIdx.x * 256 + threadIdx.x;
    if (e >= E) return;
    int d = dst[e];
    int pos = atomicAdd(&cur[d], 1);
    csr_src[pos] = src[e];
}

// ===== Layer 0 fused gather: 2 nodes/wave, 32 lanes/node, 16B/lane, =====
// ===== fully-predicated unroll-4; noise added here (NT load)        =====
__global__ __launch_bounds__(256) void agg0_kernel(
    const int* __restrict__ off, const int* __restrict__ csr_src,
    const unsigned short* __restrict__ h,   // [N,256] bf16
    const float* __restrict__ el,           // [N,4]
    const float* __restrict__ er,
    const float* __restrict__ b0, const float* __restrict__ noise,
    unsigned short* __restrict__ out, int N) {
    int gt = blockIdx.x * 256 + threadIdx.x;
    int n = gt >> 5;                // 32 threads per node
    if (n >= N) return;
    const int lane = gt & 31;
    const int hd = lane >> 3;       // 8 lanes per head
    const int f0 = lane << 3;       // 8 features per lane
    const float ern = er[(size_t)n * 4 + hd];
    const int beg = off[n];
    const int last = off[n + 1] - 1;   // deg >= 1 (self-loop)
    float acc[8] = {0.f, 0.f, 0.f, 0.f, 0.f, 0.f, 0.f, 0.f};
    float l = 0.f;
    for (int p = beg; p <= last; p += 4) {
        int i1 = p + 1, i2 = p + 2, i3 = p + 3;
        const bool v1 = i1 <= last, v2 = i2 <= last, v3 = i3 <= last;
        i1 = v1 ? i1 : last;
        i2 = v2 ? i2 : last;
        i3 = v3 ? i3 : last;
        const int s0 = csr_src[p],  s1 = csr_src[i1];
        const int s2 = csr_src[i2], s3 = csr_src[i3];
        float e0 = el[(size_t)s0 * 4 + hd] + ern;
        float e1 = el[(size_t)s1 * 4 + hd] + ern;
        float e2 = el[(size_t)s2 * 4 + hd] + ern;
        float e3 = el[(size_t)s3 * 4 + hd] + ern;
        const uint4 u0 = *(const uint4*)(h + (size_t)s0 * HD0 + f0);
        const uint4 u1 = *(const uint4*)(h + (size_t)s1 * HD0 + f0);
        const uint4 u2 = *(const uint4*)(h + (size_t)s2 * HD0 + f0);
        const uint4 u3 = *(const uint4*)(h + (size_t)s3 * HD0 + f0);
        e0 = e0 > 0.f ? e0 : 0.2f * e0;
        e1 = e1 > 0.f ? e1 : 0.2f * e1;
        e2 = e2 > 0.f ? e2 : 0.2f * e2;
        e3 = e3 > 0.f ? e3 : 0.2f * e3;
        const float w0 = __expf(e0);
        const float w1 = v1 ? __expf(e1) : 0.f;
        const float w2 = v2 ? __expf(e2) : 0.f;
        const float w3 = v3 ? __expf(e3) : 0.f;
        acc8(acc, u0, w0);
        acc8(acc, u1, w1);
        acc8(acc, u2, w2);
        acc8(acc, u3, w3);
        l += (w0 + w1) + (w2 + w3);
    }
    const float rd = 1.f / l;
    const float4 ba = *(const float4*)(b0 + f0);
    const float4 bb = *(const float4*)(b0 + f0 + 4);
    const f4 na = __builtin_nontemporal_load((const f4*)(noise + (size_t)n * HD0 + f0));
    const f4 nb = __builtin_nontemporal_load((const f4*)(noise + (size_t)n * HD0 + f0 + 4));
    float o[8];
    o[0] = acc[0] * rd + ba.x;
    o[1] = acc[1] * rd + ba.y;
    o[2] = acc[2] * rd + ba.z;
    o[3] = acc[3] * rd + ba.w;
    o[4] = acc[4] * rd + bb.x;
    o[5] = acc[5] * rd + bb.y;
    o[6] = acc[6] * rd + bb.z;
    o[7] = acc[7] * rd + bb.w;
#pragma unroll
    for (int j = 0; j < 8; ++j) o[j] = o[j] > 0.f ? o[j] : 0.01f * o[j];
    o[0] += NOISE_SCALE * na.x;
    o[1] += NOISE_SCALE * na.y;
    o[2] += NOISE_SCALE * na.z;
    o[3] += NOISE_SCALE * na.w;
    o[4] += NOISE_SCALE * nb.x;
    o[5] += NOISE_SCALE * nb.y;
    o[6] += NOISE_SCALE * nb.z;
    o[7] += NOISE_SCALE * nb.w;
    uint4 ov;
    ov.x = (unsigned)f2bf(o[0]) | ((unsigned)f2bf(o[1]) << 16);
    ov.y = (unsigned)f2bf(o[2]) | ((unsigned)f2bf(o[3]) << 16);
    ov.z = (unsigned)f2bf(o[4]) | ((unsigned)f2bf(o[5]) << 16);
    ov.w = (unsigned)f2bf(o[6]) | ((unsigned)f2bf(o[7]) << 16);
    *(uint4*)(out + (size_t)n * HD0 + f0) = ov;
}

// ===== Layer 1 fused gather: 4 nodes/wave, 16 lanes/node, 8B/lane, =====
// ===== fully-predicated unroll-4 + bias -> fp32                    =====
__global__ __launch_bounds__(256) void agg1_kernel(
    const int* __restrict__ off, const int* __restrict__ csr_src,
    const unsigned short* __restrict__ h,   // [N,64] bf16
    const float* __restrict__ el,           // [N]
    const float* __restrict__ er,
    const float* __restrict__ b1, float* __restrict__ out, int N) {
    int gt = blockIdx.x * 256 + threadIdx.x;
    int n = gt >> 4;                // 16 threads per node
    if (n >= N) return;
    const int lane = gt & 15;
    const int f0 = lane << 2;       // 4 features per lane
    const float ern = er[n];
    const int beg = off[n];
    const int last = off[n + 1] - 1;
    float a0 = 0.f, a1 = 0.f, a2 = 0.f, a3 = 0.f, l = 0.f;
    for (int p = beg; p <= last; p += 4) {
        int i1 = p + 1, i2 = p + 2, i3 = p + 3;
        const bool v1 = i1 <= last, v2 = i2 <= last, v3 = i3 <= last;
        i1 = v1 ? i1 : last;
        i2 = v2 ? i2 : last;
        i3 = v3 ? i3 : last;
        const int s0 = csr_src[p],  s1 = csr_src[i1];
        const int s2 = csr_src[i2], s3 = csr_src[i3];
        float e0 = el[s0] + ern;
        float e1 = el[s1] + ern;
        float e2 = el[s2] + ern;
        float e3 = el[s3] + ern;
        const ushort4 u0 = *(const ushort4*)(h + (size_t)s0 * 64 + f0);
        const ushort4 u1 = *(const ushort4*)(h + (size_t)s1 * 64 + f0);
        const ushort4 u2 = *(const ushort4*)(h + (size_t)s2 * 64 + f0);
        const ushort4 u3 = *(const ushort4*)(h + (size_t)s3 * 64 + f0);
        e0 = e0 > 0.f ? e0 : 0.2f * e0;
        e1 = e1 > 0.f ? e1 : 0.2f * e1;
        e2 = e2 > 0.f ? e2 : 0.2f * e2;
        e3 = e3 > 0.f ? e3 : 0.2f * e3;
        const float w0 = __expf(e0);
        const float w1 = v1 ? __expf(e1) : 0.f;
        const float w2 = v2 ? __expf(e2) : 0.f;
        const float w3 = v3 ? __expf(e3) : 0.f;
        a0 += w0 * bf2f(u0.x) + w1 * bf2f(u1.x) + w2 * bf2f(u2.x) + w3 * bf2f(u3.x);
        a1 += w0 * bf2f(u0.y) + w1 * bf2f(u1.y) + w2 * bf2f(u2.y) + w3 * bf2f(u3.y);
        a2 += w0 * bf2f(u0.z) + w1 * bf2f(u1.z) + w2 * bf2f(u2.z) + w3 * bf2f(u3.z);
        a3 += w0 * bf2f(u0.w) + w1 * bf2f(u1.w) + w2 * bf2f(u2.w) + w3 * bf2f(u3.w);
        l += (w0 + w1) + (w2 + w3);
    }
    const float rd = 1.f / l;
    const float4 bv = *(const float4*)(b1 + f0);
    float4 o;
    o.x = a0 * rd + bv.x;
    o.y = a1 * rd + bv.y;
    o.z = a2 * rd + bv.z;
    o.w = a3 * rd + bv.w;
    *(float4*)(out + (size_t)n * 64 + f0) = o;
}

extern "C" void kernel_launch(void* const* d_in, const int* in_sizes, int n_in,
                              void* d_out, int out_size, void* d_ws, size_t ws_size,
                              hipStream_t stream) {
    const float* x     = (const float*)d_in[0];
    const int*   src   = (const int*)d_in[1];
    const int*   dst   = (const int*)d_in[2];
    const float* W0    = (const float*)d_in[3];
    const float* al0   = (const float*)d_in[4];
    const float* ar0   = (const float*)d_in[5];
    const float* b0    = (const float*)d_in[6];
    const float* W1    = (const float*)d_in[7];
    const float* al1   = (const float*)d_in[8];
    const float* ar1   = (const float*)d_in[9];
    const float* b1    = (const float*)d_in[10];
    const float* noise = (const float*)d_in[11];

    const int N = in_sizes[0] / IN_F;   // 100000
    const int E = in_sizes[1];          // 900000
    const int NB = (N + 255) / 256;

    // Workspace layout
    char* p = (char*)d_ws;
    unsigned short* h0     = (unsigned short*)p; p += (size_t)N * HD0 * 2;
    unsigned short* agg0b  = (unsigned short*)p; p += (size_t)N * HD0 * 2;
    unsigned short* h1     = (unsigned short*)p; p += (size_t)N * OUT_F * 2;
    unsigned short* W0t    = (unsigned short*)p; p += (size_t)IN_F * HD0 * 2;
    unsigned short* W1t    = (unsigned short*)p; p += (size_t)HD0 * OUT_F * 2;
    float* el     = (float*)p; p += (size_t)N * HEADS * 4;
    float* er     = (float*)p; p += (size_t)N * HEADS * 4;
    int* deg    = (int*)p; p += (size_t)N * 4;
    int* cur    = (int*)p; p += (size_t)N * 4;
    int* off    = (int*)p; p += ((size_t)N + 4) * 4;
    int* bsum   = (int*)p; p += 512 * 4;
    int* csr_src= (int*)p; p += (size_t)E * 4;

    // ---------- prep: weights + deg zero ----------
    prep_kernel<<<NB, 256, 0, stream>>>(deg, N, W0, W0t, W1, W1t);

    // ---------- CSR build ----------
    degree_kernel<<<(E + 255) / 256, 256, 0, stream>>>(dst, deg, E);
    scan_block_kernel<<<NB, 256, 0, stream>>>(deg, off, bsum, N);
    scan_partials_kernel<<<1, 512, 0, stream>>>(bsum, NB);
    add_offsets_kernel<<<NB, 256, 0, stream>>>(off, cur, bsum, N, E);
    fill_csr_kernel<<<(E + 255) / 256, 256, 0, stream>>>(src, dst, cur, csr_src, E);

    const int MB = (N + 127) / 128;   // 782

    // ---------- Layer 0 (NT=2, x cast fused into A-staging) ----------
    {
        dim3 grid(HD0 / 128, MB);
        gemm_fused_kernel<IN_F, HEADS, 2, true><<<grid, 256, 0, stream>>>(
            (const void*)x, W0t, h0, al0, ar0, el, er, N, HD0);
    }
    agg0_kernel<<<(unsigned)(((size_t)N * 32 + 255) / 256), 256, 0, stream>>>(
        off, csr_src, h0, el, er, b0, noise, agg0b, N);

    // ---------- Layer 1 ----------
    {
        dim3 grid(OUT_F / 64, MB);  // NT=1
        gemm_fused_kernel<HD0, 1, 1, false><<<grid, 256, 0, stream>>>(
            (const void*)agg0b, W1t, h1, al1, ar1, el, er, N, OUT_F);
    }
    agg1_kernel<<<(unsigned)(((size_t)N * 16 + 255) / 256), 256, 0, stream>>>(
        off, csr_src, h1, el, er, b1, (float*)d_out, N);
}